// Round 1
// baseline (1026.571 us; speedup 1.0000x reference)
//
#include <hip/hip_runtime.h>
#include <math.h>

// Problem constants
#define WIN   20
#define HOPSZ 10
#define NWIN  399          // (4000-20)/10+1
#define NCH   2
#define TLEN  4000
#define NFR   798          // NCH*NWIN
#define DOUT  10
#define KOPS  6
#define NB    2048
#define EPSV  1e-6f
#define RIDGE 1e-3f

// packed upper triangle index for 10x10, i<=j
#define TIX(i,j) ((i)*10 - (i)*((i)+1)/2 + (j))

// ---------------------------------------------------------------- Jacobi 10x10
// A: packed upper triangle (55), V: row-major 10x10 (100). On exit diag(A)=evals,
// columns of V are eigenvectors: A_orig = V diag V^T.
__device__ __forceinline__ void jacobi10(float* A, float* V) {
#pragma unroll
  for (int i = 0; i < 10; i++)
#pragma unroll
    for (int j = 0; j < 10; j++) V[i * 10 + j] = (i == j) ? 1.0f : 0.0f;

  for (int sweep = 0; sweep < 10; ++sweep) {
    float off = 0.f, dia = 0.f;
#pragma unroll
    for (int p = 0; p < 10; p++) {
      float d = A[TIX(p, p)];
      dia += d * d;
#pragma unroll
      for (int q = p + 1; q < 10; q++) {
        float o = A[TIX(p, q)];
        off += o * o;
      }
    }
    if (__ballot((off > 1e-14f * (dia + 2.f * off)) && (off > 1e-37f)) == 0ull) break;

#pragma unroll
    for (int p = 0; p < 10; p++) {
#pragma unroll
      for (int q = p + 1; q < 10; q++) {
        float apq = A[TIX(p, q)];
        float app = A[TIX(p, p)];
        float aqq = A[TIX(q, q)];
        bool rot = fabsf(apq) > 1e-32f;
        float theta = (aqq - app) / (2.0f * (rot ? apq : 1.0f));
        float t = copysignf(1.0f, theta) / (fabsf(theta) + sqrtf(theta * theta + 1.0f));
        float c = 1.0f / sqrtf(t * t + 1.0f);
        float s = t * c;
        if (!rot) { c = 1.0f; s = 0.0f; t = 0.0f; }
#pragma unroll
        for (int j = 0; j < 10; j++) {
          if (j == p || j == q) continue;
          const int jp = (j < p) ? TIX(j, p) : TIX(p, j);
          const int jq = (j < q) ? TIX(j, q) : TIX(q, j);
          float ajp = A[jp], ajq = A[jq];
          A[jp] = c * ajp - s * ajq;
          A[jq] = s * ajp + c * ajq;
        }
        A[TIX(p, p)] = app - t * apq;
        A[TIX(q, q)] = aqq + t * apq;
        A[TIX(p, q)] = 0.0f;
#pragma unroll
        for (int i = 0; i < 10; i++) {
          float vip = V[i * 10 + p], viq = V[i * 10 + q];
          V[i * 10 + p] = c * vip - s * viq;
          V[i * 10 + q] = s * vip + c * viq;
        }
      }
    }
  }
}

// ---------------------------------------------------------------- sparsemax
__global__ void k_sparsemax(const float* __restrict__ alphas, float* __restrict__ wgt) {
  if (threadIdx.x != 0 || blockIdx.x != 0) return;
  for (int r = 0; r < 3; r++) {
    float z[KOPS], zs[KOPS];
    for (int i = 0; i < KOPS; i++) { z[i] = alphas[r * KOPS + i]; zs[i] = z[i]; }
    for (int i = 0; i < KOPS; i++)
      for (int j = i + 1; j < KOPS; j++)
        if (zs[j] > zs[i]) { float tm = zs[i]; zs[i] = zs[j]; zs[j] = tm; }
    float zc[KOPS]; float acc = 0.f; int cnt = 0;
    for (int i = 0; i < KOPS; i++) {
      acc += zs[i];
      zc[i] = acc;
      if (1.0f + (float)(i + 1) * zs[i] > acc) cnt++;
    }
    float tau = (zc[cnt - 1] - 1.0f) / (float)cnt;
    for (int i = 0; i < KOPS; i++) wgt[r * KOPS + i] = fmaxf(z[i] - tau, 0.0f);
  }
}

// ---------------------------------------------------------------- cov + stem
__global__ __launch_bounds__(256) void k_cov_stem(const float* __restrict__ x,
                                                  const float* __restrict__ Wst,
                                                  float* __restrict__ Sout) {
  __shared__ float xl[NCH * TLEN];
  __shared__ float raw[210];
  __shared__ float csum[WIN];
  __shared__ float cov[WIN * WIN];
  __shared__ float wst[WIN * WIN];
  __shared__ float tmp[WIN * WIN];
  int b = blockIdx.x, tid = threadIdx.x;
  for (int i = tid; i < NCH * TLEN; i += 256) xl[i] = x[b * NCH * TLEN + i];
  for (int i = tid; i < WIN * WIN; i += 256) wst[i] = Wst[i];
  __syncthreads();
  if (tid < 210) {
    int t0 = tid, d = 0;
    while (t0 >= WIN - d) { t0 -= WIN - d; d++; }
    int e = d + t0;
    float acc = 0.f;
    for (int c = 0; c < NCH; c++) {
      const float* xc = xl + c * TLEN;
      for (int w = 0; w < NWIN; w++) acc += xc[w * HOPSZ + d] * xc[w * HOPSZ + e];
    }
    raw[tid] = acc;
  }
  if (tid >= 224 && tid < 224 + WIN) {
    int d = tid - 224;
    float acc = 0.f;
    for (int c = 0; c < NCH; c++) {
      const float* xc = xl + c * TLEN;
      for (int w = 0; w < NWIN; w++) acc += xc[w * HOPSZ + d];
    }
    csum[d] = acc;
  }
  __syncthreads();
  if (tid < 210) {
    int t0 = tid, d = 0;
    while (t0 >= WIN - d) { t0 -= WIN - d; d++; }
    int e = d + t0;
    float v = (raw[tid] - csum[d] * csum[e] * (1.0f / (float)NFR)) * (1.0f / (float)(NFR - 1));
    if (d == e) v += RIDGE;
    cov[d * WIN + e] = v;
    cov[e * WIN + d] = v;
  }
  __syncthreads();
  for (int o = tid; o < WIN * WIN; o += 256) {
    int j = o / WIN, l = o % WIN;
    float acc = 0.f;
    for (int k2 = 0; k2 < WIN; k2++) acc += cov[j * WIN + k2] * wst[k2 * WIN + l];
    tmp[o] = acc;
  }
  __syncthreads();
  for (int o = tid; o < WIN * WIN; o += 256) {
    int i = o / WIN, l = o % WIN;
    float acc = 0.f;
    for (int j = 0; j < WIN; j++) acc += wst[j * WIN + i] * tmp[j * WIN + l];
    if (i == l) acc += RIDGE;
    Sout[b * WIN * WIN + o] = acc;
  }
}

// ---------------------------------------------------------------- cand = W^T S W + ridge I (packed, element-major)
template <int DIN>
__global__ __launch_bounds__(256) void k_cand(const float* __restrict__ Sin,
                                              const float* __restrict__ Wop,
                                              float* __restrict__ cand, int BC) {
  __shared__ float Sl[DIN * DIN];
  __shared__ float Wl[12 * DIN * DOUT];
  __shared__ float Tl[12 * DIN * DOUT];
  int bc = blockIdx.x, tid = threadIdx.x;
  for (int i = tid; i < DIN * DIN; i += 256) Sl[i] = Sin[bc * DIN * DIN + i];
  for (int i = tid; i < 12 * DIN * DOUT; i += 256) Wl[i] = Wop[i];
  __syncthreads();
  for (int o = tid; o < 12 * DIN * DOUT; o += 256) {
    int mk = o / (DIN * DOUT);
    int r = o % (DIN * DOUT);
    int j = r / DOUT, n = r % DOUT;
    float acc = 0.f;
    for (int l = 0; l < DIN; l++) acc += Sl[j * DIN + l] * Wl[mk * DIN * DOUT + l * DOUT + n];
    Tl[o] = acc;
  }
  __syncthreads();
  int NM = 12 * BC;
  for (int o = tid; o < 12 * 55; o += 256) {
    int mk = o / 55, t = o % 55;
    int t0 = t, i = 0;
    while (t0 >= DOUT - i) { t0 -= DOUT - i; i++; }
    int n = i + t0;
    float acc = 0.f;
    for (int j = 0; j < DIN; j++)
      acc += Wl[mk * DIN * DOUT + j * DOUT + i] * Tl[mk * DIN * DOUT + j * DOUT + n];
    if (i == n) acc += RIDGE;
    cand[t * NM + mk * BC + bc] = acc;
  }
}

// ---------------------------------------------------------------- logm in place (element-major packed)
__global__ __launch_bounds__(64, 1) void k_logm(float* __restrict__ cand, int NM) {
  int mat = blockIdx.x * 64 + threadIdx.x;
  bool act = mat < NM;
  float A[55];
  if (act) {
#pragma unroll
    for (int t = 0; t < 55; t++) A[t] = cand[t * NM + mat];
  } else {
#pragma unroll
    for (int t = 0; t < 55; t++) A[t] = 0.f;
#pragma unroll
    for (int r = 0; r < 10; r++) A[TIX(r, r)] = 1.0f;
  }
  float V[100];
  jacobi10(A, V);
  float f[10];
#pragma unroll
  for (int r = 0; r < 10; r++) f[r] = logf(fmaxf(A[TIX(r, r)], EPSV));
  if (act) {
#pragma unroll
    for (int i = 0; i < 10; i++)
#pragma unroll
      for (int n = i; n < 10; n++) {
        float acc = 0.f;
#pragma unroll
        for (int r = 0; r < 10; r++) acc += (V[i * 10 + r] * f[r]) * V[n * 10 + r];
        cand[TIX(i, n) * NM + mat] = acc;
      }
  }
}

// ---------------------------------------------------------------- expm of weighted sum -> new S (full 10x10)
__global__ __launch_bounds__(64, 1) void k_expm(const float* __restrict__ L,
                                                const float* __restrict__ wgt,
                                                float* __restrict__ Sout, int BC, int C) {
  int id = blockIdx.x * 64 + threadIdx.x;  // id = m*BC + bc
  int NE = 2 * BC;
  bool act = id < NE;
  int m = act ? id / BC : 0;
  int bc = act ? id % BC : 0;
  int NM = 12 * BC;
  float A[55];
  if (act) {
    float w[KOPS];
#pragma unroll
    for (int k2 = 0; k2 < KOPS; k2++) w[k2] = wgt[k2];
#pragma unroll
    for (int t = 0; t < 55; t++) {
      float acc = 0.f;
#pragma unroll
      for (int k2 = 0; k2 < KOPS; k2++) acc += w[k2] * L[t * NM + (m * KOPS + k2) * BC + bc];
      A[t] = acc;
    }
  } else {
#pragma unroll
    for (int t = 0; t < 55; t++) A[t] = 0.f;
#pragma unroll
    for (int r = 0; r < 10; r++) A[TIX(r, r)] = 1.0f;
  }
  float V[100];
  jacobi10(A, V);
  float f[10];
#pragma unroll
  for (int r = 0; r < 10; r++) f[r] = expf(A[TIX(r, r)]);
  if (act) {
    int b = bc / C, c = bc % C;
    int C2 = 2 * C;
    float* out = Sout + (size_t)(b * C2 + m * C + c) * 100;
#pragma unroll
    for (int i = 0; i < 10; i++)
#pragma unroll
      for (int n = i; n < 10; n++) {
        float acc = 0.f;
#pragma unroll
        for (int r = 0; r < 10; r++) acc += (V[i * 10 + r] * f[r]) * V[n * 10 + r];
        out[i * 10 + n] = acc;
        out[n * 10 + i] = acc;
      }
  }
}

// ---------------------------------------------------------------- final logm -> feature vector (full 100 per matrix)
__global__ __launch_bounds__(64, 1) void k_logm_final(const float* __restrict__ Sin,
                                                      float* __restrict__ Lf) {
  int id = blockIdx.x * 64 + threadIdx.x;  // b*8+ch, total 16384
  float A[55];
#pragma unroll
  for (int i = 0; i < 10; i++)
#pragma unroll
    for (int n = i; n < 10; n++) A[TIX(i, n)] = Sin[(size_t)id * 100 + i * 10 + n];
  float V[100];
  jacobi10(A, V);
  float f[10];
#pragma unroll
  for (int r = 0; r < 10; r++) f[r] = logf(fmaxf(A[TIX(r, r)], EPSV));
#pragma unroll
  for (int i = 0; i < 10; i++)
#pragma unroll
    for (int n = i; n < 10; n++) {
      float acc = 0.f;
#pragma unroll
      for (int r = 0; r < 10; r++) acc += (V[i * 10 + r] * f[r]) * V[n * 10 + r];
      Lf[(size_t)id * 100 + i * 10 + n] = acc;
      Lf[(size_t)id * 100 + n * 10 + i] = acc;
    }
}

// ---------------------------------------------------------------- classifier
__global__ __launch_bounds__(256) void k_cls(const float* __restrict__ Lf,
                                             const float* __restrict__ Wc,
                                             const float* __restrict__ bcv,
                                             float* __restrict__ out) {
  int id = blockIdx.x * 256 + threadIdx.x;
  if (id >= NB * 10) return;
  int b = id / 10, cls = id % 10;
  float acc = bcv[cls];
  const float* lrow = Lf + (size_t)b * 800;
  for (int v = 0; v < 800; v++) acc += lrow[v] * Wc[v * 10 + cls];
  out[id] = acc;
}

// ---------------------------------------------------------------- launch
extern "C" void kernel_launch(void* const* d_in, const int* in_sizes, int n_in,
                              void* d_out, int out_size, void* d_ws, size_t ws_size,
                              hipStream_t stream) {
  const float* x      = (const float*)d_in[0];
  const float* Wst    = (const float*)d_in[1];
  const float* Wop0   = (const float*)d_in[2];
  const float* Wop1   = (const float*)d_in[3];
  const float* Wop2   = (const float*)d_in[4];
  const float* alphas = (const float*)d_in[5];
  const float* Wcls   = (const float*)d_in[6];
  const float* bcls   = (const float*)d_in[7];
  float* out = (float*)d_out;

  // workspace layout (floats): wgt(64) | Sa(2048*800) | Sb(2048*800) | cand(55*12*2048*4)
  float* ws   = (float*)d_ws;
  float* wgt  = ws;
  float* Sa   = ws + 64;
  float* Sb   = Sa + (size_t)NB * 800;
  float* cand = Sb + (size_t)NB * 800;
  // total = 64 + 2*1638400 + 5406720 floats = ~34.7 MB

  k_sparsemax<<<1, 64, 0, stream>>>(alphas, wgt);
  k_cov_stem<<<NB, 256, 0, stream>>>(x, Wst, Sa);

  // cell 0: S (B,1,20,20) -> (B,2,10,10)
  k_cand<20><<<NB, 256, 0, stream>>>(Sa, Wop0, cand, NB);
  k_logm<<<(12 * NB) / 64, 64, 0, stream>>>(cand, 12 * NB);
  k_expm<<<(2 * NB) / 64, 64, 0, stream>>>(cand, wgt + 0, Sb, NB, 1);

  // cell 1: (B,2,10,10) -> (B,4,10,10)
  k_cand<10><<<NB * 2, 256, 0, stream>>>(Sb, Wop1, cand, NB * 2);
  k_logm<<<(12 * NB * 2) / 64, 64, 0, stream>>>(cand, 12 * NB * 2);
  k_expm<<<(2 * NB * 2) / 64, 64, 0, stream>>>(cand, wgt + 6, Sa, NB * 2, 2);

  // cell 2: (B,4,10,10) -> (B,8,10,10)
  k_cand<10><<<NB * 4, 256, 0, stream>>>(Sa, Wop2, cand, NB * 4);
  k_logm<<<(12 * NB * 4) / 64, 64, 0, stream>>>(cand, 12 * NB * 4);
  k_expm<<<(2 * NB * 4) / 64, 64, 0, stream>>>(cand, wgt + 12, Sb, NB * 4, 4);

  // final logm -> features in Sa (B*800)
  k_logm_final<<<(8 * NB) / 64, 64, 0, stream>>>(Sb, Sa);

  // classifier
  k_cls<<<(NB * 10 + 255) / 256, 256, 0, stream>>>(Sa, Wcls, bcls, out);
}